// Round 1
// baseline (1393.231 us; speedup 1.0000x reference)
//
#include <hip/hip_runtime.h>

#define H_ 16
#define HD_ 64
#define S_ 2048
#define D_ 1024
#define B_ 2
#define R_ 32
#define M_ 4096   // B*S
#define N3_ 3072  // 3*D

// Weff[o*IN+i] = W[o*IN+i] + (1/32) * sum_r A[i*R+r] * Bm[r*OUT+o]
// (y = x @ W.T + (x@A)@Bm/32  ==  x @ Weff.T with this Weff)
__global__ void fold_kernel(const float* __restrict__ W,
                            const float* __restrict__ A,
                            const float* __restrict__ Bm,
                            float* __restrict__ out, int OUT, int IN) {
  int idx = blockIdx.x * 256 + threadIdx.x;
  int o = idx / IN;
  int i = idx - o * IN;
  float s = 0.f;
#pragma unroll
  for (int r = 0; r < R_; ++r) s += A[i * R_ + r] * Bm[r * OUT + o];
  out[idx] = W[idx] + s * (1.0f / 32.0f);
}

// Y[M,N] = X[M,K] @ W[N,K]^T   (both row-major, K contiguous in both)
// 128x128 tile, BK=8, 256 threads, 8x8 microtile per thread.
__global__ __launch_bounds__(256) void gemm_nt_kernel(
    const float* __restrict__ X, const float* __restrict__ W,
    float* __restrict__ Y, int M, int N, int K) {
  __shared__ float As[8][128 + 4];
  __shared__ float Bs[8][128 + 4];
  const int t = threadIdx.x;
  const int tx = t & 15;
  const int ty = t >> 4;
  const int bm = blockIdx.y * 128;
  const int bn = blockIdx.x * 128;
  const int lr = t >> 1;          // 0..127
  const int lc = (t & 1) * 4;     // 0 or 4
  const float* Xp = X + (size_t)(bm + lr) * K + lc;
  const float* Wp = W + (size_t)(bn + lr) * K + lc;
  float acc[8][8];
#pragma unroll
  for (int i = 0; i < 8; ++i)
#pragma unroll
    for (int j = 0; j < 8; ++j) acc[i][j] = 0.f;

  for (int k0 = 0; k0 < K; k0 += 8) {
    const float4 av = *(const float4*)(Xp + k0);
    const float4 bv = *(const float4*)(Wp + k0);
    __syncthreads();
    As[lc + 0][lr] = av.x; As[lc + 1][lr] = av.y;
    As[lc + 2][lr] = av.z; As[lc + 3][lr] = av.w;
    Bs[lc + 0][lr] = bv.x; Bs[lc + 1][lr] = bv.y;
    Bs[lc + 2][lr] = bv.z; Bs[lc + 3][lr] = bv.w;
    __syncthreads();
#pragma unroll
    for (int kk = 0; kk < 8; ++kk) {
      const float4 a0 = *(const float4*)&As[kk][ty * 8];
      const float4 a1 = *(const float4*)&As[kk][ty * 8 + 4];
      const float4 b0 = *(const float4*)&Bs[kk][tx * 8];
      const float4 b1 = *(const float4*)&Bs[kk][tx * 8 + 4];
      const float a[8] = {a0.x, a0.y, a0.z, a0.w, a1.x, a1.y, a1.z, a1.w};
      const float b[8] = {b0.x, b0.y, b0.z, b0.w, b1.x, b1.y, b1.z, b1.w};
#pragma unroll
      for (int i = 0; i < 8; ++i)
#pragma unroll
        for (int j = 0; j < 8; ++j) acc[i][j] = fmaf(a[i], b[j], acc[i][j]);
    }
  }
#pragma unroll
  for (int i = 0; i < 8; ++i) {
    float* yp = Y + (size_t)(bm + ty * 8 + i) * N + bn + tx * 8;
    *(float4*)yp = make_float4(acc[i][0], acc[i][1], acc[i][2], acc[i][3]);
    *(float4*)(yp + 4) = make_float4(acc[i][4], acc[i][5], acc[i][6], acc[i][7]);
  }
}

// Flash attention, fp32. Block = (b,h,q-tile of 64). 256 threads (16x16),
// each thread owns 4 q-rows x 4 cols. P round-trips through LDS. KV buffer
// reused between K phase ([d][key]) and V phase ([key][d]) -> 52 KB LDS.
__global__ __launch_bounds__(256) void attn_kernel(
    const float* __restrict__ qkv, const float* __restrict__ alibi,
    const float* __restrict__ pad, float* __restrict__ ctx) {
  __shared__ float Qs[HD_][64 + 4];   // [d][q]
  __shared__ float KVs[64][64 + 4];   // K: [d][key] ; V: [key][d]
  __shared__ float Ps[64][64 + 4];    // [key][q]
  const int t = threadIdx.x;
  const int tx = t & 15;
  const int ty = t >> 4;
  const int bh = blockIdx.y;
  const int b = bh >> 4;
  const int h = bh & 15;
  const int q0 = blockIdx.x * 64;
  const int ldr = t >> 2;         // tile row 0..63
  const int ldc = (t & 3) << 4;   // 0,16,32,48

  {  // Q tile, transposed store
    const float* qp = qkv + (size_t)(b * S_ + q0 + ldr) * N3_ + h * HD_ + ldc;
#pragma unroll
    for (int c = 0; c < 4; ++c) {
      const float4 v = *(const float4*)(qp + 4 * c);
      Qs[ldc + 4 * c + 0][ldr] = v.x;
      Qs[ldc + 4 * c + 1][ldr] = v.y;
      Qs[ldc + 4 * c + 2][ldr] = v.z;
      Qs[ldc + 4 * c + 3][ldr] = v.w;
    }
  }
  float O[4][4];
  float mrun[4], lrun[4];
#pragma unroll
  for (int i = 0; i < 4; ++i) {
    mrun[i] = -1e30f;
    lrun[i] = 0.f;
#pragma unroll
    for (int j = 0; j < 4; ++j) O[i][j] = 0.f;
  }

  for (int kt = 0; kt < S_ / 64; ++kt) {
    const int k0 = kt * 64;
    __syncthreads();  // prev iter's Ps/KVs reads done
    {  // K tile, transposed store [d][key]
      const float* kp =
          qkv + (size_t)(b * S_ + k0 + ldr) * N3_ + D_ + h * HD_ + ldc;
#pragma unroll
      for (int c = 0; c < 4; ++c) {
        const float4 v = *(const float4*)(kp + 4 * c);
        KVs[ldc + 4 * c + 0][ldr] = v.x;
        KVs[ldc + 4 * c + 1][ldr] = v.y;
        KVs[ldc + 4 * c + 2][ldr] = v.z;
        KVs[ldc + 4 * c + 3][ldr] = v.w;
      }
    }
    __syncthreads();
    float s[4][4];
#pragma unroll
    for (int i = 0; i < 4; ++i)
#pragma unroll
      for (int j = 0; j < 4; ++j) s[i][j] = 0.f;
#pragma unroll 8
    for (int d = 0; d < HD_; ++d) {
      const float4 qa = *(const float4*)&Qs[d][ty * 4];
      const float4 kb = *(const float4*)&KVs[d][tx * 4];
      const float aq[4] = {qa.x, qa.y, qa.z, qa.w};
      const float bk[4] = {kb.x, kb.y, kb.z, kb.w};
#pragma unroll
      for (int i = 0; i < 4; ++i)
#pragma unroll
        for (int j = 0; j < 4; ++j) s[i][j] = fmaf(aq[i], bk[j], s[i][j]);
    }
    // bias: scores*0.125 + alibi[h,q,k] + pad[b,k]
    const float4 pv = *(const float4*)(pad + (size_t)b * S_ + k0 + tx * 4);
    const float padv[4] = {pv.x, pv.y, pv.z, pv.w};
#pragma unroll
    for (int i = 0; i < 4; ++i) {
      const float* ap =
          alibi + (size_t)(h * S_ + q0 + ty * 4 + i) * S_ + k0 + tx * 4;
      const float4 av = *(const float4*)ap;
      s[i][0] = fmaf(s[i][0], 0.125f, av.x + padv[0]);
      s[i][1] = fmaf(s[i][1], 0.125f, av.y + padv[1]);
      s[i][2] = fmaf(s[i][2], 0.125f, av.z + padv[2]);
      s[i][3] = fmaf(s[i][3], 0.125f, av.w + padv[3]);
    }
    // online softmax; rows owned by the 16 lanes sharing ty (intra-wave)
#pragma unroll
    for (int i = 0; i < 4; ++i) {
      float rm = fmaxf(fmaxf(s[i][0], s[i][1]), fmaxf(s[i][2], s[i][3]));
#pragma unroll
      for (int off = 1; off < 16; off <<= 1)
        rm = fmaxf(rm, __shfl_xor(rm, off, 16));
      const float mnew = fmaxf(mrun[i], rm);
      const float alpha = __expf(mrun[i] - mnew);
      mrun[i] = mnew;
      float rs = 0.f;
#pragma unroll
      for (int j = 0; j < 4; ++j) {
        s[i][j] = __expf(s[i][j] - mnew);
        rs += s[i][j];
      }
#pragma unroll
      for (int off = 1; off < 16; off <<= 1) rs += __shfl_xor(rs, off, 16);
      lrun[i] = lrun[i] * alpha + rs;
#pragma unroll
      for (int j = 0; j < 4; ++j) O[i][j] *= alpha;
    }
    // P -> LDS transposed [key][q]
#pragma unroll
    for (int j = 0; j < 4; ++j)
      *(float4*)&Ps[tx * 4 + j][ty * 4] =
          make_float4(s[0][j], s[1][j], s[2][j], s[3][j]);
    __syncthreads();  // K reads done, Ps half-barrier 1
    {  // V tile, natural layout [key][d]
      const float* vp =
          qkv + (size_t)(b * S_ + k0 + ldr) * N3_ + 2 * D_ + h * HD_ + ldc;
#pragma unroll
      for (int c = 0; c < 4; ++c)
        *(float4*)&KVs[ldr][ldc + 4 * c] = *(const float4*)(vp + 4 * c);
    }
    __syncthreads();  // V visible, Ps visible
#pragma unroll 8
    for (int kk = 0; kk < 64; ++kk) {
      const float4 pp = *(const float4*)&Ps[kk][ty * 4];
      const float4 vv = *(const float4*)&KVs[kk][tx * 4];
      const float p4[4] = {pp.x, pp.y, pp.z, pp.w};
      const float v4[4] = {vv.x, vv.y, vv.z, vv.w};
#pragma unroll
      for (int i = 0; i < 4; ++i)
#pragma unroll
        for (int j = 0; j < 4; ++j) O[i][j] = fmaf(p4[i], v4[j], O[i][j]);
    }
  }
#pragma unroll
  for (int i = 0; i < 4; ++i) {
    const float inv = 1.0f / lrun[i];
    float* cp = ctx + (size_t)(b * S_ + q0 + ty * 4 + i) * D_ + h * HD_ + tx * 4;
    *(float4*)cp =
        make_float4(O[i][0] * inv, O[i][1] * inv, O[i][2] * inv, O[i][3] * inv);
  }
}

extern "C" void kernel_launch(void* const* d_in, const int* in_sizes, int n_in,
                              void* d_out, int out_size, void* d_ws,
                              size_t ws_size, hipStream_t stream) {
  const float* x     = (const float*)d_in[0];
  const float* alibi = (const float*)d_in[1];
  const float* pad   = (const float*)d_in[2];
  const float* W_qkv = (const float*)d_in[3];
  const float* A_qkv = (const float*)d_in[4];
  const float* B_qkv = (const float*)d_in[5];
  const float* W_out = (const float*)d_in[6];
  const float* A_out = (const float*)d_in[7];
  const float* B_out = (const float*)d_in[8];
  float* out = (float*)d_out;

  // workspace layout (floats): 80 MB total
  float* ws = (float*)d_ws;
  float* weffq = ws;                        // 3072*1024
  float* weffo = weffq + (size_t)N3_ * D_;  // 1024*1024
  float* qkv   = weffo + (size_t)D_ * D_;   // 4096*3072
  float* ctx   = qkv + (size_t)M_ * N3_;    // 4096*1024

  fold_kernel<<<(N3_ * D_) / 256, 256, 0, stream>>>(W_qkv, A_qkv, B_qkv, weffq,
                                                    N3_, D_);
  fold_kernel<<<(D_ * D_) / 256, 256, 0, stream>>>(W_out, A_out, B_out, weffo,
                                                   D_, D_);
  gemm_nt_kernel<<<dim3(N3_ / 128, M_ / 128), 256, 0, stream>>>(
      x, weffq, qkv, M_, N3_, D_);
  attn_kernel<<<dim3(S_ / 64, B_ * H_), 256, 0, stream>>>(qkv, alibi, pad, ctx);
  gemm_nt_kernel<<<dim3(D_ / 128, M_ / 128), 256, 0, stream>>>(
      ctx, weffo, out, M_, D_, D_);
}

// Round 2
// 625.838 us; speedup vs baseline: 2.2262x; 2.2262x over previous
//
#include <hip/hip_runtime.h>

#define H_ 16
#define HD_ 64
#define S_ 2048
#define D_ 1024
#define B_ 2
#define R_ 32
#define M_ 4096   // B*S
#define N3_ 3072  // 3*D

typedef __attribute__((ext_vector_type(8))) short short8;
typedef __attribute__((ext_vector_type(4))) float f32x4;
typedef unsigned short u16;
typedef __attribute__((ext_vector_type(4))) unsigned short u16x4;

__device__ inline u16 f2bf(float f) {  // RNE float->bf16
  unsigned u = __float_as_uint(f);
  u += 0x7fff + ((u >> 16) & 1);
  return (u16)(u >> 16);
}

// Weff[o*IN+i] = W[o*IN+i] + (1/32) * sum_r A[i*R+r] * Bm[r*OUT+o], stored bf16
__global__ void fold_kernel(const float* __restrict__ W,
                            const float* __restrict__ A,
                            const float* __restrict__ Bm,
                            u16* __restrict__ out, int OUT, int IN) {
  int idx = blockIdx.x * 256 + threadIdx.x;
  int o = idx / IN;
  int i = idx - o * IN;
  float s = 0.f;
#pragma unroll
  for (int r = 0; r < R_; ++r) s += A[i * R_ + r] * Bm[r * OUT + o];
  out[idx] = f2bf(W[idx] + s * (1.0f / 32.0f));
}

__global__ void cvt_kernel(const float* __restrict__ x, u16* __restrict__ xb) {
  int i = (blockIdx.x * 256 + threadIdx.x) * 4;
  const float4 v = *(const float4*)(x + i);
  u16x4 o = {f2bf(v.x), f2bf(v.y), f2bf(v.z), f2bf(v.w)};
  *(u16x4*)(xb + i) = o;
}

// Y[M,N] = X[M,K] @ W[N,K]^T, bf16 in, fp32 acc. 128x128 tile, BK=32,
// 4 waves in 2x2, each wave 64x64 (4x4 mfma 16x16x32 tiles).
// EPI==0: store fp32 Y.  EPI==1: split-store qkv as Q,K [b,h,s,d] bf16 and
// V transposed [b,h,d,s] bf16.
template <int EPI>
__global__ __launch_bounds__(256) void gemm_bf16(
    const u16* __restrict__ X, const u16* __restrict__ Wb,
    float* __restrict__ Yf, u16* __restrict__ Qb, u16* __restrict__ Kb,
    u16* __restrict__ Vtb, int M, int N, int K) {
  __shared__ u16 As[128][40];
  __shared__ u16 Bs[128][40];
  const int t = threadIdx.x;
  const int lane = t & 63;
  const int w = t >> 6;
  const int quad = lane >> 4;
  const int l = lane & 15;
  const int wh = w >> 1;   // m half
  const int ww = w & 1;    // n half
  const int bm = blockIdx.y * 128;
  const int bn = blockIdx.x * 128;
  const int srow = t >> 1;
  const int soff = (t & 1) * 16;
  const u16* Xp = X + (size_t)(bm + srow) * K + soff;
  const u16* Wp = Wb + (size_t)(bn + srow) * K + soff;
  f32x4 acc[4][4];
#pragma unroll
  for (int i = 0; i < 4; ++i)
#pragma unroll
    for (int j = 0; j < 4; ++j) acc[i][j] = (f32x4){0.f, 0.f, 0.f, 0.f};

  for (int k0 = 0; k0 < K; k0 += 32) {
    const short8 xa = *(const short8*)(Xp + k0);
    const short8 xc = *(const short8*)(Xp + k0 + 8);
    const short8 wa = *(const short8*)(Wp + k0);
    const short8 wc = *(const short8*)(Wp + k0 + 8);
    __syncthreads();
    *(short8*)&As[srow][soff] = xa;
    *(short8*)&As[srow][soff + 8] = xc;
    *(short8*)&Bs[srow][soff] = wa;
    *(short8*)&Bs[srow][soff + 8] = wc;
    __syncthreads();
    short8 af[4], bf[4];
#pragma unroll
    for (int mt = 0; mt < 4; ++mt)
      af[mt] = *(const short8*)&As[wh * 64 + mt * 16 + l][quad * 8];
#pragma unroll
    for (int nt = 0; nt < 4; ++nt)
      bf[nt] = *(const short8*)&Bs[ww * 64 + nt * 16 + l][quad * 8];
#pragma unroll
    for (int mt = 0; mt < 4; ++mt)
#pragma unroll
      for (int nt = 0; nt < 4; ++nt)
        acc[mt][nt] = __builtin_amdgcn_mfma_f32_16x16x32_bf16(
            af[mt], bf[nt], acc[mt][nt], 0, 0, 0);
  }
#pragma unroll
  for (int mt = 0; mt < 4; ++mt) {
#pragma unroll
    for (int nt = 0; nt < 4; ++nt) {
      const int m0 = bm + wh * 64 + mt * 16 + quad * 4;
      const int n = bn + ww * 64 + nt * 16 + l;
      if (EPI == 0) {
#pragma unroll
        for (int r = 0; r < 4; ++r)
          Yf[(size_t)(m0 + r) * N + n] = acc[mt][nt][r];
      } else {
        const int b = m0 >> 11;
        const int s0 = m0 & 2047;
        const int part = n >> 10;
        const int h = (n & 1023) >> 6;
        const int d = n & 63;
        if (part == 0) {
#pragma unroll
          for (int r = 0; r < 4; ++r)
            Qb[((size_t)(b * 16 + h) * 2048 + s0 + r) * 64 + d] =
                f2bf(acc[mt][nt][r]);
        } else if (part == 1) {
#pragma unroll
          for (int r = 0; r < 4; ++r)
            Kb[((size_t)(b * 16 + h) * 2048 + s0 + r) * 64 + d] =
                f2bf(acc[mt][nt][r]);
        } else {
          u16x4 pv = {f2bf(acc[mt][nt][0]), f2bf(acc[mt][nt][1]),
                      f2bf(acc[mt][nt][2]), f2bf(acc[mt][nt][3])};
          *(u16x4*)(Vtb + ((size_t)(b * 16 + h) * 64 + d) * 2048 + s0) = pv;
        }
      }
    }
  }
}

// Flash attention on MFMA. Block = (b, q-tile 128, h), 256 thr / 4 waves.
// Wave w owns q rows [w*32, w*32+32). KV-tile 64 staged in LDS.
__global__ __launch_bounds__(256) void attn_mfma(
    const u16* __restrict__ Qb, const u16* __restrict__ Kb,
    const u16* __restrict__ Vtb, const float* __restrict__ alibi,
    const float* __restrict__ pad, u16* __restrict__ ctxb) {
  __shared__ u16 KL[64][72];
  __shared__ u16 VL[64][72];
  __shared__ u16 PL[4][32][72];
  const int t = threadIdx.x;
  const int lane = t & 63;
  const int w = t >> 6;
  const int quad = lane >> 4;
  const int l = lane & 15;
  const int b = blockIdx.x;
  const int q0 = blockIdx.y * 128;
  const int h = blockIdx.z;
  const int bh = b * 16 + h;
  const int srow = t >> 2;       // staging row 0..63
  const int sq = (t & 3) * 16;   // staging col offset (u16)

  // Q fragments straight from global, reused across all KV tiles.
  short8 qf[2][2];
#pragma unroll
  for (int mt = 0; mt < 2; ++mt)
#pragma unroll
    for (int kq = 0; kq < 2; ++kq)
      qf[mt][kq] = *(const short8*)(Qb +
          ((size_t)bh * 2048 + q0 + w * 32 + mt * 16 + l) * 64 + kq * 32 +
          quad * 8);

  f32x4 Ou[2][4];
  float mrun[2][4], lrun[2][4];
#pragma unroll
  for (int mt = 0; mt < 2; ++mt) {
#pragma unroll
    for (int r = 0; r < 4; ++r) { mrun[mt][r] = -1e30f; lrun[mt][r] = 0.f; }
#pragma unroll
    for (int dn = 0; dn < 4; ++dn) Ou[mt][dn] = (f32x4){0.f, 0.f, 0.f, 0.f};
  }

  const u16* Kg = Kb + ((size_t)bh * 2048) * 64;
  const u16* Vg = Vtb + ((size_t)bh * 64) * 2048;

  for (int kt = 0; kt < S_ / 64; ++kt) {
    const int k0 = kt * 64;
    // global loads first (overlap with the barrier wait)
    const short8 kv0 = *(const short8*)(Kg + (size_t)(k0 + srow) * 64 + sq);
    const short8 kv1 = *(const short8*)(Kg + (size_t)(k0 + srow) * 64 + sq + 8);
    const short8 vv0 = *(const short8*)(Vg + (size_t)srow * 2048 + k0 + sq);
    const short8 vv1 = *(const short8*)(Vg + (size_t)srow * 2048 + k0 + sq + 8);
    __syncthreads();
    *(short8*)&KL[srow][sq] = kv0;
    *(short8*)&KL[srow][sq + 8] = kv1;
    *(short8*)&VL[srow][sq] = vv0;
    *(short8*)&VL[srow][sq + 8] = vv1;
    __syncthreads();

    // QK^T
    short8 kf[4][2];
#pragma unroll
    for (int nt = 0; nt < 4; ++nt)
#pragma unroll
      for (int kq = 0; kq < 2; ++kq)
        kf[nt][kq] = *(const short8*)&KL[nt * 16 + l][kq * 32 + quad * 8];
    f32x4 sc[2][4];
#pragma unroll
    for (int mt = 0; mt < 2; ++mt)
#pragma unroll
      for (int nt = 0; nt < 4; ++nt) {
        f32x4 c = {0.f, 0.f, 0.f, 0.f};
        c = __builtin_amdgcn_mfma_f32_16x16x32_bf16(qf[mt][0], kf[nt][0], c, 0, 0, 0);
        c = __builtin_amdgcn_mfma_f32_16x16x32_bf16(qf[mt][1], kf[nt][1], c, 0, 0, 0);
        sc[mt][nt] = c;
      }

    // bias: *0.125 + alibi[h,q,k] + pad[b,k]
    float padv[4];
#pragma unroll
    for (int nt = 0; nt < 4; ++nt) padv[nt] = pad[(size_t)b * S_ + k0 + nt * 16 + l];
#pragma unroll
    for (int mt = 0; mt < 2; ++mt)
#pragma unroll
      for (int nt = 0; nt < 4; ++nt) {
        const float* ap = alibi +
            ((size_t)h * S_ + q0 + w * 32 + mt * 16 + quad * 4) * S_ + k0 +
            nt * 16 + l;
#pragma unroll
        for (int r = 0; r < 4; ++r)
          sc[mt][nt][r] = fmaf(sc[mt][nt][r], 0.125f,
                               ap[(size_t)r * S_] + padv[nt]);
      }

    // online softmax per q-row (row = w*32 + mt*16 + quad*4 + r)
#pragma unroll
    for (int mt = 0; mt < 2; ++mt) {
#pragma unroll
      for (int r = 0; r < 4; ++r) {
        float rm = fmaxf(fmaxf(sc[mt][0][r], sc[mt][1][r]),
                         fmaxf(sc[mt][2][r], sc[mt][3][r]));
#pragma unroll
        for (int off = 1; off < 16; off <<= 1)
          rm = fmaxf(rm, __shfl_xor(rm, off, 16));
        const float mnew = fmaxf(mrun[mt][r], rm);
        const float alpha = __expf(mrun[mt][r] - mnew);
        mrun[mt][r] = mnew;
        float rs = 0.f;
#pragma unroll
        for (int nt = 0; nt < 4; ++nt) {
          const float e = __expf(sc[mt][nt][r] - mnew);
          sc[mt][nt][r] = e;
          rs += e;
        }
#pragma unroll
        for (int off = 1; off < 16; off <<= 1) rs += __shfl_xor(rs, off, 16);
        lrun[mt][r] = lrun[mt][r] * alpha + rs;
#pragma unroll
        for (int dn = 0; dn < 4; ++dn) Ou[mt][dn][r] *= alpha;
      }
    }

    // P -> wave-private LDS (bf16), A-operand layout [q_local][key_local]
#pragma unroll
    for (int mt = 0; mt < 2; ++mt)
#pragma unroll
      for (int nt = 0; nt < 4; ++nt)
#pragma unroll
        for (int r = 0; r < 4; ++r)
          PL[w][mt * 16 + quad * 4 + r][nt * 16 + l] = f2bf(sc[mt][nt][r]);

    // PV  (same-wave LDS write->read; in-order DS pipe, no barrier)
    short8 vf[4][2], pf[2][2];
#pragma unroll
    for (int dn = 0; dn < 4; ++dn)
#pragma unroll
      for (int kq = 0; kq < 2; ++kq)
        vf[dn][kq] = *(const short8*)&VL[dn * 16 + l][kq * 32 + quad * 8];
#pragma unroll
    for (int mt = 0; mt < 2; ++mt)
#pragma unroll
      for (int kq = 0; kq < 2; ++kq)
        pf[mt][kq] = *(const short8*)&PL[w][mt * 16 + l][kq * 32 + quad * 8];
#pragma unroll
    for (int mt = 0; mt < 2; ++mt)
#pragma unroll
      for (int dn = 0; dn < 4; ++dn) {
        Ou[mt][dn] = __builtin_amdgcn_mfma_f32_16x16x32_bf16(
            pf[mt][0], vf[dn][0], Ou[mt][dn], 0, 0, 0);
        Ou[mt][dn] = __builtin_amdgcn_mfma_f32_16x16x32_bf16(
            pf[mt][1], vf[dn][1], Ou[mt][dn], 0, 0, 0);
      }
  }

  // epilogue: ctx bf16 [b, s, h*64+d]
#pragma unroll
  for (int mt = 0; mt < 2; ++mt) {
#pragma unroll
    for (int r = 0; r < 4; ++r) {
      const float inv = 1.0f / lrun[mt][r];
      const int s = q0 + w * 32 + mt * 16 + quad * 4 + r;
#pragma unroll
      for (int dn = 0; dn < 4; ++dn)
        ctxb[((size_t)b * 2048 + s) * 1024 + h * 64 + dn * 16 + l] =
            f2bf(Ou[mt][dn][r] * inv);
    }
  }
}

extern "C" void kernel_launch(void* const* d_in, const int* in_sizes, int n_in,
                              void* d_out, int out_size, void* d_ws,
                              size_t ws_size, hipStream_t stream) {
  const float* x     = (const float*)d_in[0];
  const float* alibi = (const float*)d_in[1];
  const float* pad   = (const float*)d_in[2];
  const float* W_qkv = (const float*)d_in[3];
  const float* A_qkv = (const float*)d_in[4];
  const float* B_qkv = (const float*)d_in[5];
  const float* W_out = (const float*)d_in[6];
  const float* A_out = (const float*)d_in[7];
  const float* B_out = (const float*)d_in[8];
  float* out = (float*)d_out;

  u16* ws = (u16*)d_ws;
  u16* xb    = ws;                               // 4096*1024
  u16* weffq = xb + (size_t)M_ * D_;             // 3072*1024
  u16* weffo = weffq + (size_t)N3_ * D_;         // 1024*1024
  u16* Qb    = weffo + (size_t)D_ * D_;          // 2*16*2048*64
  u16* Kb    = Qb + (size_t)M_ * D_;
  u16* Vtb   = Kb + (size_t)M_ * D_;
  u16* ctxb  = Vtb + (size_t)M_ * D_;            // 4096*1024

  fold_kernel<<<(N3_ * D_) / 256, 256, 0, stream>>>(W_qkv, A_qkv, B_qkv, weffq,
                                                    N3_, D_);
  fold_kernel<<<(D_ * D_) / 256, 256, 0, stream>>>(W_out, A_out, B_out, weffo,
                                                   D_, D_);
  cvt_kernel<<<(M_ * D_) / 1024, 256, 0, stream>>>(x, xb);
  gemm_bf16<1><<<dim3(N3_ / 128, M_ / 128), 256, 0, stream>>>(
      xb, weffq, nullptr, Qb, Kb, Vtb, M_, N3_, D_);
  attn_mfma<<<dim3(B_, S_ / 128, H_), 256, 0, stream>>>(Qb, Kb, Vtb, alibi,
                                                        pad, ctxb);
  gemm_bf16<0><<<dim3(D_ / 128, M_ / 128), 256, 0, stream>>>(
      ctxb, weffo, out, nullptr, nullptr, nullptr, M_, D_, D_);
}